// Round 5
// baseline (554.011 us; speedup 1.0000x reference)
//
#include <hip/hip_runtime.h>
#include <hip/hip_bf16.h>

#define U_NUM 3072
#define I_NUM 3072
#define N_NODES 6144
#define NNZV (N_NODES*64)
#define HEADS 8
#define BKT_CAP 128
#define NBLK 768

typedef _Float16 f16x8 __attribute__((ext_vector_type(8)));
typedef _Float16 f16x4 __attribute__((ext_vector_type(4)));
typedef _Float16 f16x2 __attribute__((ext_vector_type(2)));
typedef float f32x4 __attribute__((ext_vector_type(4)));

#define MFMA16(a,b,c) __builtin_amdgcn_mfma_f32_16x16x16f16((a),(b),(c),0,0,0)

// ---- device-scope grid barrier (all NBLK blocks co-resident via launch_bounds) ----
__device__ __forceinline__ void gridbar(int* bar, int target){
    __syncthreads();
    if (threadIdx.x == 0){
        __threadfence();
        atomicAdd(bar, 1);
        while (__hip_atomic_load(bar, __ATOMIC_RELAXED, __HIP_MEMORY_SCOPE_AGENT) < target)
            __builtin_amdgcn_s_sleep(2);
        __threadfence();
    }
    __syncthreads();
}

// ---- 16x16 output tile via 8-step MFMA chain, A row-major lda=128, W row-major 128 ----
__device__ __forceinline__ f32x4 mfma_chain(const _Float16* __restrict__ A,
                                            const _Float16* __restrict__ W,
                                            int r0, int c0, int l16, int g){
    const _Float16* ap = A + (r0+l16)*128 + 4*g;
    const _Float16* bp = W + (c0+l16)*128 + 4*g;
    f32x4 acc = {};
    #pragma unroll
    for (int kk = 0; kk < 8; kk++)
        acc = MFMA16(*(const f16x4*)(ap + kk*16), *(const f16x4*)(bp + kk*16), acc);
    return acc;
}

// ---- SPMM row: 2 edges per wave iteration, b64 gathers ----
template<int ADDF>
__device__ __forceinline__ void spmm_row(int r, const int* __restrict__ cnt,
                                         const int2* __restrict__ bkt,
                                         const _Float16* __restrict__ X,
                                         _Float16* __restrict__ outp, int lane){
    int n = cnt[r]; n = (n > BKT_CAP) ? BKT_CAP : n;
    const int2* em = bkt + r*BKT_CAP;
    int c4 = (lane & 31)*4, esel = lane >> 5;
    f32x4 acc = {};
    int j = 0;
    for (; j + 8 <= n; j += 8){
        #pragma unroll
        for (int u = 0; u < 4; u++){
            int2 m = em[j + 2*u + esel];
            f16x4 x = *(const f16x4*)(X + m.x*128 + c4);
            float v = __int_as_float(m.y);
            acc[0] += v*(float)x[0]; acc[1] += v*(float)x[1];
            acc[2] += v*(float)x[2]; acc[3] += v*(float)x[3];
        }
    }
    for (; j < n; j += 2){
        int jj = j + esel;
        if (jj < n){
            int2 m = em[jj];
            f16x4 x = *(const f16x4*)(X + m.x*128 + c4);
            float v = __int_as_float(m.y);
            acc[0] += v*(float)x[0]; acc[1] += v*(float)x[1];
            acc[2] += v*(float)x[2]; acc[3] += v*(float)x[3];
        }
    }
    #pragma unroll
    for (int q = 0; q < 4; q++) acc[q] += __shfl_xor(acc[q], 32);
    if (lane < 32){
        if (ADDF){
            f16x4 f = *(const f16x4*)(X + r*128 + c4);
            acc[0] += (float)f[0]; acc[1] += (float)f[1];
            acc[2] += (float)f[2]; acc[3] += (float)f[3];
        }
        f16x4 o = {(_Float16)acc[0], (_Float16)acc[1], (_Float16)acc[2], (_Float16)acc[3]};
        *(f16x4*)(outp + r*128 + c4) = o;
    }
}

__global__ __launch_bounds__(256, 3) void k_mega(
    const float* __restrict__ uE, const float* __restrict__ iE,
    const float* __restrict__ lv, const int* __restrict__ lr, const int* __restrict__ lc,
    const float* __restrict__ a1w, const float* __restrict__ a1b,
    const float* __restrict__ a2w, const float* __restrict__ a2b,
    const float* __restrict__ ipw, const float* __restrict__ ipb,
    const float* __restrict__ opw, const float* __restrict__ opb,
    float* __restrict__ outp,
    _Float16* __restrict__ F16, _Float16* __restrict__ P16,
    _Float16* __restrict__ agg1, _Float16* __restrict__ attO,
    _Float16* __restrict__ inter, _Float16* __restrict__ agg2,
    _Float16* __restrict__ Wbuf, int2* __restrict__ bkt,
    int* __restrict__ cnt, int* __restrict__ bar){

    __shared__ _Float16 Klds[2][128][20];
    __shared__ _Float16 Vt[2][16][134];

    const int tid = threadIdx.x, lane = tid & 63, wv = tid >> 6;
    const int l16 = lane & 15, g = lane >> 4;
    const _Float16* a1w16 = Wbuf;
    const _Float16* a2w16 = Wbuf + 16384;
    const _Float16* opw16 = Wbuf + 32768;
    const _Float16* ipw16 = Wbuf + 49152;

    // ---------------- P0: cvt features + weights, bucket-scatter edges ----------------
    {
        int gtid = blockIdx.x*256 + tid;
        for (int i = gtid; i < 221184 + NNZV; i += NBLK*256){
            if (i < 196608){
                int i4 = i*4;
                const float* src = (i4 < 393216) ? (uE + i4) : (iE + i4 - 393216);
                float4 v = *(const float4*)src;
                f16x4 h = {(_Float16)v.x,(_Float16)v.y,(_Float16)v.z,(_Float16)v.w};
                *(f16x4*)(F16 + i4) = h;
            } else if (i < 221184){
                int i4 = (i - 196608)*4;
                const float* src; int off;
                if      (i4 < 16384){ src = a1w; off = i4; }
                else if (i4 < 32768){ src = a2w; off = i4 - 16384; }
                else if (i4 < 49152){ src = opw; off = i4 - 32768; }
                else                { src = ipw; off = i4 - 49152; }
                float4 v = *(const float4*)(src + off);
                f16x4 h = {(_Float16)v.x,(_Float16)v.y,(_Float16)v.z,(_Float16)v.w};
                *(f16x4*)(Wbuf + i4) = h;
            } else {
                int e = i - 221184;
                int r = lr[e];
                int p = atomicAdd(&cnt[r], 1);
                if (p < BKT_CAP) bkt[r*BKT_CAP + p] = make_int2(lc[e], __float_as_int(lv[e]));
            }
        }
    }
    gridbar(bar, NBLK*1);

    // ---------------- P1: spmm1 (F16->agg1) + proj (F16->P16), fused ----------------
    {
        int gw = blockIdx.x*4 + wv;
        for (int it = gw; it < 6144 + 9216; it += NBLK*4){
            if (it < 6144){
                spmm_row<1>(it, cnt, bkt, F16, agg1, lane);
            } else {
                int pid = it - 6144;
                int cb = pid / 384, rb = pid % 384;
                int r0 = rb*16, c0 = cb*16;
                f32x4 acc = mfma_chain(F16, ipw16, r0, c0, l16, g);
                float bb = ipb[c0+l16];
                float scale = (c0 < 128) ? 0.25f : 1.f;
                #pragma unroll
                for (int r = 0; r < 4; r++)
                    P16[(r0+4*g+r)*384 + c0+l16] = (_Float16)((acc[r]+bb)*scale);
            }
        }
    }
    gridbar(bar, NBLK*2);

    // ---------------- P2: attention (one (qtile,head,side) item per block) ----------------
    {
        int it = blockIdx.x;
        int qt = it % 48, h = (it/48) % 8, side = it / 384;
        int qbase  = side * U_NUM;
        int kvbase = (1 - side) * U_NUM;

        int qrow = qt*64 + wv*16 + l16;
        f16x4 qf = *(const f16x4*)(P16 + (qbase+qrow)*384 + h*16 + 4*g);  // pre-scaled 0.25

        f32x4 acc = {}, lsacc = {};
        const f32x4 zero = {};
        const f16x4 ones = {(_Float16)1.f,(_Float16)1.f,(_Float16)1.f,(_Float16)1.f};
        const f16x2 h2 = {(_Float16)0.5f,(_Float16)0.5f};
        const f16x2 o2 = {(_Float16)1.f,(_Float16)1.f};

        int skey = tid >> 1, spart = tid & 1;
        const _Float16* kvsrc = P16 + (kvbase + skey)*384 + h*16 + spart*8;

        {
            f16x8 kv = *(const f16x8*)(kvsrc + 128);
            f16x8 vv = *(const f16x8*)(kvsrc + 256);
            *(f16x4*)&Klds[0][skey][spart*8]     = *(f16x4*)&kv;
            *(f16x4*)&Klds[0][skey][spart*8 + 4] = *((f16x4*)&kv + 1);
            #pragma unroll
            for (int j = 0; j < 8; j++) Vt[0][spart*8+j][skey] = vv[j];
        }
        __syncthreads();

        for (int t = 0; t < 24; t++){
            int cur = t & 1;
            if (t + 1 < 24){
                const _Float16* src = kvsrc + (t+1)*128*384;
                f16x8 kv = *(const f16x8*)(src + 128);
                f16x8 vv = *(const f16x8*)(src + 256);
                int nxt = cur ^ 1;
                *(f16x4*)&Klds[nxt][skey][spart*8]     = *(f16x4*)&kv;
                *(f16x4*)&Klds[nxt][skey][spart*8 + 4] = *((f16x4*)&kv + 1);
                #pragma unroll
                for (int j = 0; j < 8; j++) Vt[nxt][spart*8+j][skey] = vv[j];
            }
            #pragma unroll
            for (int kb = 0; kb < 8; kb++){
                f16x4 kf = *(const f16x4*)&Klds[cur][kb*16 + l16][4*g];
                f32x4 st = MFMA16(kf, qf, zero);
                f16x2 s01 = __builtin_bit_cast(f16x2, __builtin_amdgcn_cvt_pkrtz(st[0], st[1]));
                f16x2 s23 = __builtin_bit_cast(f16x2, __builtin_amdgcn_cvt_pkrtz(st[2], st[3]));
                f16x2 p01 = s01*(s01*h2 + o2) + o2;
                f16x2 p23 = s23*(s23*h2 + o2) + o2;
                f16x4 pf; pf[0]=p01[0]; pf[1]=p01[1]; pf[2]=p23[0]; pf[3]=p23[1];
                f16x4 vf = *(const f16x4*)&Vt[cur][l16][kb*16 + 4*g];
                acc   = MFMA16(pf, vf,   acc);
                lsacc = MFMA16(pf, ones, lsacc);
            }
            __syncthreads();
        }
        #pragma unroll
        for (int r = 0; r < 4; r++){
            int qn = qbase + qt*64 + wv*16 + 4*g + r;
            attO[qn*128 + h*16 + l16] = (_Float16)(acc[r] / lsacc[r]);
        }
    }
    gridbar(bar, NBLK*3);

    // ---------------- P3: out-proj + square (attO -> inter) ----------------
    {
        int it = blockIdx.x*4 + wv;          // 3072 items, 1/wave
        int cb = it / 384, rb = it % 384;
        int r0 = rb*16, c0 = cb*16;
        f32x4 acc = mfma_chain(attO, opw16, r0, c0, l16, g);
        float bb = opb[c0+l16];
        #pragma unroll
        for (int r = 0; r < 4; r++){
            float v = acc[r] + bb;
            inter[(r0+4*g+r)*128 + c0+l16] = (_Float16)(v*v);
        }
    }
    gridbar(bar, NBLK*4);

    // ---------------- P4: spmm0 (inter -> agg2) ----------------
    {
        int gw = blockIdx.x*4 + wv;
        for (int it = gw; it < 6144; it += NBLK*4)
            spmm_row<0>(it, cnt, bkt, inter, agg2, lane);
    }
    gridbar(bar, NBLK*5);

    // ---------------- P5: final (relu(agg1@a1)+relu(agg2@a2) | embd copy) ----------------
    {
        int it = blockIdx.x*4 + wv;          // 3072 items, 1/wave
        int cb = it / 384, rb = it % 384;
        int r0 = rb*16, c0 = cb*16;
        f32x4 acc1 = mfma_chain(agg1, a1w16, r0, c0, l16, g);
        f32x4 acc2 = mfma_chain(agg2, a2w16, r0, c0, l16, g);
        float b1 = a1b[c0+l16], b2 = a2b[c0+l16];
        #pragma unroll
        for (int r = 0; r < 4; r++){
            int row = r0 + 4*g + r, col = c0 + l16;
            outp[row*256 + 128 + col] = fmaxf(acc1[r]+b1, 0.f) + fmaxf(acc2[r]+b2, 0.f);
            const float* e = (row < U_NUM) ? (uE + row*128) : (iE + (row - U_NUM)*128);
            outp[row*256 + col] = e[col];
        }
    }
}

extern "C" void kernel_launch(void* const* d_in, const int* in_sizes, int n_in,
                              void* d_out, int out_size, void* d_ws, size_t ws_size,
                              hipStream_t stream){
    const float* uE  = (const float*)d_in[2];
    const float* iE  = (const float*)d_in[3];
    const float* lv  = (const float*)d_in[4];
    const int*   lr  = (const int*)d_in[5];
    const int*   lc  = (const int*)d_in[6];
    const float* a1w = (const float*)d_in[7];
    const float* a1b = (const float*)d_in[8];
    const float* a2w = (const float*)d_in[9];
    const float* a2b = (const float*)d_in[10];
    const float* ipw = (const float*)d_in[11];
    const float* ipb = (const float*)d_in[12];
    const float* opw = (const float*)d_in[13];
    const float* opb = (const float*)d_in[14];
    float* outp = (float*)d_out;

    char* B = (char*)d_ws;
    _Float16* F16   = (_Float16*)(B);                  // 1,572,864
    _Float16* P16   = (_Float16*)(B + 1572864);        // 4,718,592
    _Float16* agg1  = (_Float16*)(B + 6291456);        // 1,572,864
    _Float16* attO  = (_Float16*)(B + 7864320);        // 1,572,864
    _Float16* inter = (_Float16*)(B + 9437184);        // 1,572,864
    _Float16* agg2  = (_Float16*)(B + 11010048);       // 1,572,864
    _Float16* Wbuf  = (_Float16*)(B + 12582912);       // 196,608
    int2*     bkt   = (int2*)(B + 12779520);           // 6,291,456
    int*      cnt   = (int*)(B + 19070976);            // 24,576
    int*      bar   = (int*)(B + 19095552);            // 4

    (void)hipMemsetAsync(cnt, 0, (N_NODES+1)*sizeof(int), stream);
    k_mega<<<NBLK, 256, 0, stream>>>(uE, iE, lv, lr, lc, a1w, a1b, a2w, a2b,
                                     ipw, ipb, opw, opb, outp,
                                     F16, P16, agg1, attO, inter, agg2,
                                     Wbuf, bkt, cnt, bar);
}

// Round 7
// 130.155 us; speedup vs baseline: 4.2566x; 4.2566x over previous
//
#include <hip/hip_runtime.h>
#include <hip/hip_bf16.h>

#define U_NUM 3072
#define I_NUM 3072
#define N_NODES 6144
#define NNZV (N_NODES*64)
#define HEADS 8
#define BKT_CAP 128

typedef _Float16 f16x8 __attribute__((ext_vector_type(8)));
typedef _Float16 f16x4 __attribute__((ext_vector_type(4)));
typedef _Float16 f16x2 __attribute__((ext_vector_type(2)));
typedef float f32x4 __attribute__((ext_vector_type(4)));

#define MFMA16(a,b,c) __builtin_amdgcn_mfma_f32_16x16x16f16((a),(b),(c),0,0,0)

// ---------- zero cnt ----------
__global__ void k_zero(int* __restrict__ cnt){
    cnt[blockIdx.x*256 + threadIdx.x] = 0;
}

// ---------- fused prep: cvt features, cvt weights, bucket-scatter edges ----------
__global__ void k_prep(const float* __restrict__ uE, const float* __restrict__ iE,
                       const float* __restrict__ a1, const float* __restrict__ a2,
                       const float* __restrict__ op, const float* __restrict__ ip,
                       _Float16* __restrict__ F, _Float16* __restrict__ Wdst,
                       const int* __restrict__ lr, const int* __restrict__ lc,
                       const float* __restrict__ lv,
                       int* __restrict__ cnt, int2* __restrict__ bkt){
    int b = blockIdx.x, tid = threadIdx.x;
    if (b < 768){
        int i4 = (b*256 + tid)*4;                      // features: 786432 elems
        const float* src = (i4 < 393216) ? (uE + i4) : (iE + i4 - 393216);
        float4 v = *(const float4*)src;
        f16x4 h = {(_Float16)v.x,(_Float16)v.y,(_Float16)v.z,(_Float16)v.w};
        *(f16x4*)(F + i4) = h;
    } else if (b < 864){
        int i4 = ((b-768)*256 + tid)*4;                // weights: 98304 elems
        const float* src; int off;
        if      (i4 < 16384){ src = a1; off = i4; }
        else if (i4 < 32768){ src = a2; off = i4 - 16384; }
        else if (i4 < 49152){ src = op; off = i4 - 32768; }
        else                { src = ip; off = i4 - 49152; }
        float4 v = *(const float4*)(src + off);
        f16x4 h = {(_Float16)v.x,(_Float16)v.y,(_Float16)v.z,(_Float16)v.w};
        *(f16x4*)(Wdst + i4) = h;
    } else {
        int e = (b-864)*256 + tid;                     // edges: 393216
        int r = lr[e];
        int p = atomicAdd(&cnt[r], 1);
        if (p < BKT_CAP) bkt[r*BKT_CAP + p] = make_int2(lc[e], __float_as_int(lv[e]));
    }
}

// ---------- SPMM row helper: 2 edges per wave iteration, b64 gathers ----------
template<int ADDF>
__device__ __forceinline__ void spmm_row(int r, const int* __restrict__ cnt,
                                         const int2* __restrict__ bkt,
                                         const _Float16* __restrict__ X,
                                         _Float16* __restrict__ outp, int lane){
    int n = cnt[r]; n = (n > BKT_CAP) ? BKT_CAP : n;
    const int2* em = bkt + r*BKT_CAP;
    int c4 = (lane & 31)*4, esel = lane >> 5;
    f32x4 acc = {};
    int j = 0;
    for (; j + 8 <= n; j += 8){
        #pragma unroll
        for (int u = 0; u < 4; u++){
            int2 m = em[j + 2*u + esel];
            f16x4 x = *(const f16x4*)(X + m.x*128 + c4);
            float v = __int_as_float(m.y);
            acc[0] += v*(float)x[0]; acc[1] += v*(float)x[1];
            acc[2] += v*(float)x[2]; acc[3] += v*(float)x[3];
        }
    }
    for (; j < n; j += 2){
        int jj = j + esel;
        if (jj < n){
            int2 m = em[jj];
            f16x4 x = *(const f16x4*)(X + m.x*128 + c4);
            float v = __int_as_float(m.y);
            acc[0] += v*(float)x[0]; acc[1] += v*(float)x[1];
            acc[2] += v*(float)x[2]; acc[3] += v*(float)x[3];
        }
    }
    #pragma unroll
    for (int q = 0; q < 4; q++) acc[q] += __shfl_xor(acc[q], 32);
    if (lane < 32){
        if (ADDF){
            f16x4 f = *(const f16x4*)(X + r*128 + c4);
            acc[0] += (float)f[0]; acc[1] += (float)f[1];
            acc[2] += (float)f[2]; acc[3] += (float)f[3];
        }
        f16x4 o = {(_Float16)acc[0], (_Float16)acc[1], (_Float16)acc[2], (_Float16)acc[3]};
        *(f16x4*)(outp + r*128 + c4) = o;
    }
}

// ---- 16x16 output tile via 8-step MFMA chain ----
__device__ __forceinline__ f32x4 mfma_chain(const _Float16* __restrict__ A,
                                            const _Float16* __restrict__ W,
                                            int r0, int c0, int l16, int g){
    const _Float16* ap = A + (r0+l16)*128 + 4*g;
    const _Float16* bp = W + (c0+l16)*128 + 4*g;
    f32x4 acc = {};
    #pragma unroll
    for (int kk = 0; kk < 8; kk++)
        acc = MFMA16(*(const f16x4*)(ap + kk*16), *(const f16x4*)(bp + kk*16), acc);
    return acc;
}

// ---------- merged: spmm1 (F16->agg1) + proj (F16->P16) ----------
__global__ void k_sp1proj(const int* __restrict__ cnt, const int2* __restrict__ bkt,
                          const _Float16* __restrict__ F16, _Float16* __restrict__ agg1,
                          const _Float16* __restrict__ ipw16, const float* __restrict__ ipb,
                          _Float16* __restrict__ P16){
    int tid = threadIdx.x, lane = tid & 63, wv = tid >> 6;
    if (blockIdx.x < 1536){
        int wid = blockIdx.x*4 + wv;
        spmm_row<1>(wid, cnt, bkt, F16, agg1, lane);
    } else {
        int l16 = lane & 15, g = lane >> 4;
        int pid = (blockIdx.x - 1536)*4 + wv;          // 9216 tiles
        int cb = pid / 384, rb = pid % 384;
        int r0 = rb*16, c0 = cb*16;
        f32x4 acc = mfma_chain(F16, ipw16, r0, c0, l16, g);
        float bb = ipb[c0+l16];
        float scale = (c0 < 128) ? 0.25f : 1.f;
        #pragma unroll
        for (int r = 0; r < 4; r++)
            P16[(r0+4*g+r)*384 + c0+l16] = (_Float16)((acc[r]+bb)*scale);
    }
}

// ---------- fused attention: QB=64, 4 waves, ones-MFMA lsum, packed-f16 poly ----------
__global__ __launch_bounds__(256) void k_attn(const _Float16* __restrict__ P,
                                              _Float16* __restrict__ attO){
    __shared__ _Float16 Klds[2][128][20];
    __shared__ _Float16 Vt[2][16][134];
    int h = blockIdx.y, side = blockIdx.z;
    int tid = threadIdx.x, lane = tid & 63, wv = tid >> 6;
    int l16 = lane & 15, g = lane >> 4;
    int qbase  = side * U_NUM;
    int kvbase = (1 - side) * U_NUM;

    int qrow = blockIdx.x*64 + wv*16 + l16;
    f16x4 qf = *(const f16x4*)(P + (qbase+qrow)*384 + h*16 + 4*g);   // pre-scaled 0.25

    f32x4 acc = {}, lsacc = {};
    const f32x4 zero = {};
    const f16x4 ones = {(_Float16)1.f,(_Float16)1.f,(_Float16)1.f,(_Float16)1.f};
    const f16x2 h2 = {(_Float16)0.5f,(_Float16)0.5f};
    const f16x2 o2 = {(_Float16)1.f,(_Float16)1.f};

    int skey = tid >> 1, spart = tid & 1;
    const _Float16* kvsrc = P + (kvbase + skey)*384 + h*16 + spart*8;

    {
        f16x8 kv = *(const f16x8*)(kvsrc + 128);
        f16x8 vv = *(const f16x8*)(kvsrc + 256);
        *(f16x4*)&Klds[0][skey][spart*8]     = *(f16x4*)&kv;
        *(f16x4*)&Klds[0][skey][spart*8 + 4] = *((f16x4*)&kv + 1);
        #pragma unroll
        for (int j = 0; j < 8; j++) Vt[0][spart*8+j][skey] = vv[j];
    }
    __syncthreads();

    for (int t = 0; t < 24; t++){
        int cur = t & 1;
        if (t + 1 < 24){
            const _Float16* src = kvsrc + (t+1)*128*384;
            f16x8 kv = *(const f16x8*)(src + 128);
            f16x8 vv = *(const f16x8*)(src + 256);
            int nxt = cur ^ 1;
            *(f16x4*)&Klds[nxt][skey][spart*8]     = *(f16x4*)&kv;
            *(f16x4*)&Klds[nxt][skey][spart*8 + 4] = *((f16x4*)&kv + 1);
            #pragma unroll
            for (int j = 0; j < 8; j++) Vt[nxt][spart*8+j][skey] = vv[j];
        }
        #pragma unroll
        for (int kb = 0; kb < 8; kb++){
            f16x4 kf = *(const f16x4*)&Klds[cur][kb*16 + l16][4*g];
            f32x4 st = MFMA16(kf, qf, zero);
            f16x2 s01 = __builtin_bit_cast(f16x2, __builtin_amdgcn_cvt_pkrtz(st[0], st[1]));
            f16x2 s23 = __builtin_bit_cast(f16x2, __builtin_amdgcn_cvt_pkrtz(st[2], st[3]));
            f16x2 p01 = s01*(s01*h2 + o2) + o2;
            f16x2 p23 = s23*(s23*h2 + o2) + o2;
            f16x4 pf; pf[0]=p01[0]; pf[1]=p01[1]; pf[2]=p23[0]; pf[3]=p23[1];
            f16x4 vf = *(const f16x4*)&Vt[cur][l16][kb*16 + 4*g];
            acc   = MFMA16(pf, vf,   acc);
            lsacc = MFMA16(pf, ones, lsacc);
        }
        __syncthreads();
    }
    #pragma unroll
    for (int r = 0; r < 4; r++){
        int qn = qbase + blockIdx.x*64 + wv*16 + 4*g + r;
        attO[qn*128 + h*16 + l16] = (_Float16)(acc[r] / lsacc[r]);
    }
}

// ---------- out-proj + square ----------
__global__ void k_gemmO(const _Float16* __restrict__ A, const _Float16* __restrict__ W,
                        const float* __restrict__ bias, _Float16* __restrict__ C){
    int tid = threadIdx.x, lane = tid & 63, wv = tid >> 6;
    int l16 = lane&15, g = lane>>4;
    int r0 = blockIdx.x*64 + wv*16, c0 = blockIdx.y*16;
    f32x4 acc = mfma_chain(A, W, r0, c0, l16, g);
    float bb = bias[c0+l16];
    #pragma unroll
    for (int r = 0; r < 4; r++){
        float v = acc[r] + bb;
        C[(r0+4*g+r)*128 + c0+l16] = (_Float16)(v*v);
    }
}

// ---------- spmm0 (inter -> agg2) ----------
__global__ void k_spmm0(const int* __restrict__ cnt, const int2* __restrict__ bkt,
                        const _Float16* __restrict__ X, _Float16* __restrict__ outp){
    int wid  = (blockIdx.x*256 + threadIdx.x) >> 6;
    int lane = threadIdx.x & 63;
    spmm_row<0>(wid, cnt, bkt, X, outp, lane);
}

// ---------- final: relu(agg1@a1)+relu(agg2@a2) | embd copy ----------
__global__ void k_final(const _Float16* __restrict__ agg1, const _Float16* __restrict__ agg2,
                        const _Float16* __restrict__ a1w16, const float* __restrict__ a1b,
                        const _Float16* __restrict__ a2w16, const float* __restrict__ a2b,
                        const float* __restrict__ uE, const float* __restrict__ iE,
                        float* __restrict__ outp){
    int tid = threadIdx.x, lane = tid & 63, wv = tid >> 6;
    int l16 = lane&15, g = lane>>4;
    int r0 = blockIdx.x*64 + wv*16, c0 = blockIdx.y*16;
    f32x4 acc1 = mfma_chain(agg1, a1w16, r0, c0, l16, g);
    f32x4 acc2 = mfma_chain(agg2, a2w16, r0, c0, l16, g);
    float b1 = a1b[c0+l16], b2 = a2b[c0+l16];
    #pragma unroll
    for (int r = 0; r < 4; r++){
        int row = r0 + 4*g + r, col = c0 + l16;
        outp[row*256 + 128 + col] = fmaxf(acc1[r]+b1, 0.f) + fmaxf(acc2[r]+b2, 0.f);
        const float* e = (row < U_NUM) ? (uE + row*128) : (iE + (row - U_NUM)*128);
        outp[row*256 + col] = e[col];
    }
}

extern "C" void kernel_launch(void* const* d_in, const int* in_sizes, int n_in,
                              void* d_out, int out_size, void* d_ws, size_t ws_size,
                              hipStream_t stream){
    const float* uE  = (const float*)d_in[2];
    const float* iE  = (const float*)d_in[3];
    const float* lv  = (const float*)d_in[4];
    const int*   lr  = (const int*)d_in[5];
    const int*   lc  = (const int*)d_in[6];
    const float* a1w = (const float*)d_in[7];
    const float* a1b = (const float*)d_in[8];
    const float* a2w = (const float*)d_in[9];
    const float* a2b = (const float*)d_in[10];
    const float* ipw = (const float*)d_in[11];
    const float* ipb = (const float*)d_in[12];
    const float* opw = (const float*)d_in[13];
    const float* opb = (const float*)d_in[14];
    float* outp = (float*)d_out;

    char* B = (char*)d_ws;
    _Float16* F16   = (_Float16*)(B);                  // 1,572,864
    _Float16* P16   = (_Float16*)(B + 1572864);        // 4,718,592
    _Float16* agg1  = (_Float16*)(B + 6291456);        // 1,572,864
    _Float16* attO  = (_Float16*)(B + 7864320);        // 1,572,864
    _Float16* inter = (_Float16*)(B + 9437184);        // 1,572,864
    _Float16* agg2  = (_Float16*)(B + 11010048);       // 1,572,864
    _Float16* Wbuf  = (_Float16*)(B + 12582912);       // 196,608
    const _Float16* a1w16 = Wbuf;
    const _Float16* a2w16 = Wbuf + 16384;
    const _Float16* opw16 = Wbuf + 32768;
    const _Float16* ipw16 = Wbuf + 49152;
    int2*     bkt   = (int2*)(B + 12779520);           // 6,291,456
    int*      cnt   = (int*)(B + 19070976);            // 24,576

    k_zero<<<24, 256, 0, stream>>>(cnt);
    k_prep<<<2400, 256, 0, stream>>>(uE, iE, a1w, a2w, opw, ipw, F16, Wbuf,
                                     lr, lc, lv, cnt, bkt);
    k_sp1proj<<<3840, 256, 0, stream>>>(cnt, bkt, F16, agg1, ipw16, ipb, P16);
    k_attn<<<dim3(48, HEADS, 2), 256, 0, stream>>>(P16, attO);
    k_gemmO<<<dim3(96, 8), 256, 0, stream>>>(attO, opw16, opb, inter);
    k_spmm0<<<1536, 256, 0, stream>>>(cnt, bkt, inter, agg2);
    k_final<<<dim3(96, 8), 256, 0, stream>>>(agg1, agg2, a1w16, a1b, a2w16, a2b,
                                             uE, iE, outp);
}